// Round 2
// baseline (301.946 us; speedup 1.0000x reference)
//
#include <hip/hip_runtime.h>
#include <hip/hip_bf16.h>
#include <cstdint>

typedef __attribute__((ext_vector_type(8))) short short8;
typedef __attribute__((ext_vector_type(4))) float floatx4;

__device__ __forceinline__ float bf2f(unsigned short u) {
  union { unsigned int i; float f; } v;
  v.i = ((unsigned int)u) << 16;
  return v.f;
}
__device__ __forceinline__ unsigned short f2bf(float f) {
  union { float f; unsigned int i; } v; v.f = f;
  unsigned int r = v.i + 0x7FFFu + ((v.i >> 16) & 1u);
  return (unsigned short)(r >> 16);
}

// ---------------------------------------------------------------------------
// fp32 -> bf16 bulk convert: each thread converts 8 floats (two float4 loads,
// one 16B store). n8 = n/8.
// ---------------------------------------------------------------------------
__global__ __launch_bounds__(256) void f32_to_bf16_kernel(
    const float* __restrict__ in, unsigned short* __restrict__ out, int n8) {
  int i = blockIdx.x * blockDim.x + threadIdx.x;
  if (i >= n8) return;
  const float4* p = (const float4*)in + (size_t)i * 2;
  float4 a = p[0], b = p[1];
  short8 r;
  r[0] = (short)f2bf(a.x); r[1] = (short)f2bf(a.y);
  r[2] = (short)f2bf(a.z); r[3] = (short)f2bf(a.w);
  r[4] = (short)f2bf(b.x); r[5] = (short)f2bf(b.y);
  r[6] = (short)f2bf(b.z); r[7] = (short)f2bf(b.w);
  *(short8*)(out + (size_t)i * 8) = r;
}

// ---------------------------------------------------------------------------
// out[m][n] = sum_k A[m][k] * W[n][k] + bias[n]   (bf16 in, fp32 accum)
// One wave = one 16x16 tile; 4 waves / block. Bias fp32; OutT = bf16 or f32.
// A-frag: a[j] = A[m0 + (lane&15)][k + quad*8 + j]
// B-frag: b[j] = W[n0 + (lane&15)][k + quad*8 + j]
// C/D  : acc[r] -> out[m0 + quad*4 + r][n0 + (lane&15)]
// ---------------------------------------------------------------------------
template <typename OutT>
__global__ __launch_bounds__(256) void gemm_bias_kernel(
    const unsigned short* __restrict__ A, const unsigned short* __restrict__ W,
    const float* __restrict__ bias, OutT* __restrict__ out,
    int M, int N, int K) {
  int tile = blockIdx.x * 4 + (threadIdx.x >> 6);
  int lane = threadIdx.x & 63;
  int l16 = lane & 15;
  int quad = lane >> 4;
  int ntn = N >> 4;
  int tm = tile / ntn;
  int tn = tile - tm * ntn;

  const unsigned short* arow = A + (size_t)(tm * 16 + l16) * K + quad * 8;
  const unsigned short* wrow = W + (size_t)(tn * 16 + l16) * K + quad * 8;

  floatx4 acc = {0.f, 0.f, 0.f, 0.f};
#pragma unroll 4
  for (int k = 0; k < K; k += 32) {
    short8 a = *(const short8*)(arow + k);
    short8 b = *(const short8*)(wrow + k);
    acc = __builtin_amdgcn_mfma_f32_16x16x32_bf16(a, b, acc, 0, 0, 0);
  }

  int col = tn * 16 + l16;
  float bb = bias[col];
#pragma unroll
  for (int r = 0; r < 4; r++) {
    int row = tm * 16 + quad * 4 + r;
    float v = acc[r] + bb;
    if constexpr (sizeof(OutT) == 2)
      out[(size_t)row * N + col] = (OutT)f2bf(v);
    else
      out[(size_t)row * N + col] = (OutT)v;
  }
}

// ---------------------------------------------------------------------------
// Fused attention: per (b, h, 64 q-rows) block; 4 waves x 16 q-rows each.
// qkv (bf16 ws): [B][N][1536], q at ch h*64, k at 512+h*64, v at 1024+h*64.
// Pass A: streaming sumsq/max of scaled logits (L2 norm needs full row).
// Pass B: recompute S, p = exp((s-max)*invden), P*V via MFMA (P through LDS
// for the C-layout -> A-layout transform).
// ---------------------------------------------------------------------------
__global__ __launch_bounds__(256) void attn_kernel(
    const unsigned short* __restrict__ qkv, unsigned short* __restrict__ attn_out) {
  constexpr int NSEQ = 2048;
  constexpr int LD = 1536;
  constexpr int DM = 512;
  const float scale = 0.125f;  // hd^-0.5, hd=64

  int qb = blockIdx.x;  // 0..31
  int h = blockIdx.y;   // 0..7
  int b = blockIdx.z;   // 0..1
  int tid = threadIdx.x;
  int wave = tid >> 6;
  int lane = tid & 63;
  int l16 = lane & 15;
  int quad = lane >> 4;

  // stride 80: row step 160B -> 4-way instead of 16-way bank aliasing on the
  // column-of-rows reads; keeps 16B alignment.
  __shared__ __align__(16) unsigned short Kb[32][80];
  __shared__ __align__(16) unsigned short Vb[32][80];
  __shared__ __align__(16) unsigned short Pb[4][16][40];

  const unsigned short* base = qkv + (size_t)b * NSEQ * LD;

  int qrow = qb * 64 + wave * 16 + l16;
  const unsigned short* qptr = base + (size_t)qrow * LD + h * 64;
  short8 aq0 = *(const short8*)(qptr + quad * 8);
  short8 aq1 = *(const short8*)(qptr + 32 + quad * 8);

  int srow = tid >> 3;
  int scol = (tid & 7) * 8;
  const unsigned short* ksrc = base + (size_t)srow * LD + 512 + h * 64 + scol;
  const unsigned short* vsrc = base + (size_t)srow * LD + 1024 + h * 64 + scol;

  // ---------------- pass A: row sumsq + max ----------------
  float sumsq[4] = {0.f, 0.f, 0.f, 0.f};
  float mx[4] = {-1e30f, -1e30f, -1e30f, -1e30f};

  for (int mc = 0; mc < NSEQ; mc += 32) {
    *(short8*)(&Kb[srow][scol]) = *(const short8*)(ksrc + (size_t)mc * LD);
    __syncthreads();
#pragma unroll
    for (int st = 0; st < 2; st++) {
      floatx4 acc = {0.f, 0.f, 0.f, 0.f};
      short8 b0 = *(const short8*)(&Kb[st * 16 + l16][quad * 8]);
      short8 b1 = *(const short8*)(&Kb[st * 16 + l16][32 + quad * 8]);
      acc = __builtin_amdgcn_mfma_f32_16x16x32_bf16(aq0, b0, acc, 0, 0, 0);
      acc = __builtin_amdgcn_mfma_f32_16x16x32_bf16(aq1, b1, acc, 0, 0, 0);
#pragma unroll
      for (int r = 0; r < 4; r++) {
        float s = acc[r] * scale;
        sumsq[r] += s * s;
        mx[r] = fmaxf(mx[r], s);
      }
    }
    __syncthreads();
  }

#pragma unroll
  for (int r = 0; r < 4; r++) {
#pragma unroll
    for (int m = 1; m <= 8; m <<= 1) {
      sumsq[r] += __shfl_xor(sumsq[r], m, 64);
      mx[r] = fmaxf(mx[r], __shfl_xor(mx[r], m, 64));
    }
  }
  float invden[4];
#pragma unroll
  for (int r = 0; r < 4; r++) invden[r] = 1.f / (sqrtf(sumsq[r]) + 1e-6f);

  // ---------------- pass B: softmax + P*V ----------------
  floatx4 o0 = {0.f, 0.f, 0.f, 0.f};
  floatx4 o1 = {0.f, 0.f, 0.f, 0.f};
  floatx4 o2 = {0.f, 0.f, 0.f, 0.f};
  floatx4 o3 = {0.f, 0.f, 0.f, 0.f};
  float lsum[4] = {0.f, 0.f, 0.f, 0.f};

  for (int mc = 0; mc < NSEQ; mc += 32) {
    *(short8*)(&Kb[srow][scol]) = *(const short8*)(ksrc + (size_t)mc * LD);
    *(short8*)(&Vb[srow][scol]) = *(const short8*)(vsrc + (size_t)mc * LD);
    __syncthreads();

    float pv[2][4];
#pragma unroll
    for (int st = 0; st < 2; st++) {
      floatx4 acc = {0.f, 0.f, 0.f, 0.f};
      short8 b0 = *(const short8*)(&Kb[st * 16 + l16][quad * 8]);
      short8 b1 = *(const short8*)(&Kb[st * 16 + l16][32 + quad * 8]);
      acc = __builtin_amdgcn_mfma_f32_16x16x32_bf16(aq0, b0, acc, 0, 0, 0);
      acc = __builtin_amdgcn_mfma_f32_16x16x32_bf16(aq1, b1, acc, 0, 0, 0);
#pragma unroll
      for (int r = 0; r < 4; r++) {
        float s = acc[r] * scale;
        float p = __expf((s - mx[r]) * invden[r]);
        lsum[r] += p;
        pv[st][r] = p;
      }
    }
#pragma unroll
    for (int st = 0; st < 2; st++)
#pragma unroll
      for (int r = 0; r < 4; r++)
        Pb[wave][quad * 4 + r][st * 16 + l16] = f2bf(pv[st][r]);
    __syncthreads();

    short8 ap = *(const short8*)(&Pb[wave][l16][quad * 8]);
    short8 bv0, bv1, bv2, bv3;
#pragma unroll
    for (int j = 0; j < 8; j++) {
      bv0[j] = (short)Vb[quad * 8 + j][l16];
      bv1[j] = (short)Vb[quad * 8 + j][16 + l16];
      bv2[j] = (short)Vb[quad * 8 + j][32 + l16];
      bv3[j] = (short)Vb[quad * 8 + j][48 + l16];
    }
    o0 = __builtin_amdgcn_mfma_f32_16x16x32_bf16(ap, bv0, o0, 0, 0, 0);
    o1 = __builtin_amdgcn_mfma_f32_16x16x32_bf16(ap, bv1, o1, 0, 0, 0);
    o2 = __builtin_amdgcn_mfma_f32_16x16x32_bf16(ap, bv2, o2, 0, 0, 0);
    o3 = __builtin_amdgcn_mfma_f32_16x16x32_bf16(ap, bv3, o3, 0, 0, 0);
    __syncthreads();
  }

#pragma unroll
  for (int r = 0; r < 4; r++)
#pragma unroll
    for (int m = 1; m <= 8; m <<= 1) lsum[r] += __shfl_xor(lsum[r], m, 64);

  int nrow_base = qb * 64 + wave * 16 + quad * 4;
  size_t ob = (size_t)b * NSEQ * DM;
#pragma unroll
  for (int r = 0; r < 4; r++) {
    float inv = 1.f / lsum[r];
    size_t rowoff = ob + (size_t)(nrow_base + r) * DM + h * 64 + l16;
    attn_out[rowoff + 0] = f2bf(o0[r] * inv);
    attn_out[rowoff + 16] = f2bf(o1[r] * inv);
    attn_out[rowoff + 32] = f2bf(o2[r] * inv);
    attn_out[rowoff + 48] = f2bf(o3[r] * inv);
  }
}

// ---------------------------------------------------------------------------
extern "C" void kernel_launch(void* const* d_in, const int* in_sizes, int n_in,
                              void* d_out, int out_size, void* d_ws, size_t ws_size,
                              hipStream_t stream) {
  const float* x = (const float*)d_in[0];       // (2,2048,512) fp32
  const float* qkv_w = (const float*)d_in[1];   // (1536,512)  fp32
  const float* qkv_b = (const float*)d_in[2];   // (1536,)     fp32
  const float* proj_w = (const float*)d_in[3];  // (512,512)   fp32
  const float* proj_b = (const float*)d_in[4];  // (512,)      fp32
  float* out = (float*)d_out;                   // (2,2048,512) fp32

  // ws layout (bf16 elements)
  unsigned short* xb = (unsigned short*)d_ws;              // 4096*512
  unsigned short* qkvw_b = xb + (size_t)4096 * 512;        // 1536*512
  unsigned short* projw_b = qkvw_b + (size_t)1536 * 512;   // 512*512
  unsigned short* qkv = projw_b + (size_t)512 * 512;       // 4096*1536
  unsigned short* attn_out = qkv + (size_t)4096 * 1536;    // 4096*512

  // 0) fp32 -> bf16 converts
  {
    int n8 = (4096 * 512) / 8;
    f32_to_bf16_kernel<<<(n8 + 255) / 256, 256, 0, stream>>>(x, xb, n8);
    n8 = (1536 * 512) / 8;
    f32_to_bf16_kernel<<<(n8 + 255) / 256, 256, 0, stream>>>(qkv_w, qkvw_b, n8);
    n8 = (512 * 512) / 8;
    f32_to_bf16_kernel<<<(n8 + 255) / 256, 256, 0, stream>>>(proj_w, projw_b, n8);
  }
  // 1) qkv = x @ qkv_w^T + qkv_b   (M=4096, N=1536, K=512), bf16 out
  {
    int M = 4096, N = 1536, K = 512;
    int tiles = (M / 16) * (N / 16);
    gemm_bias_kernel<unsigned short><<<tiles / 4, 256, 0, stream>>>(
        xb, qkvw_b, qkv_b, qkv, M, N, K);
  }
  // 2) fused attention (bf16 in/out)
  attn_kernel<<<dim3(32, 8, 2), 256, 0, stream>>>(qkv, attn_out);
  // 3) out = attn_out @ proj_w^T + proj_b   (M=4096, N=512, K=512), fp32 out
  {
    int M = 4096, N = 512, K = 512;
    int tiles = (M / 16) * (N / 16);
    gemm_bias_kernel<float><<<tiles / 4, 256, 0, stream>>>(
        attn_out, projw_b, proj_b, out, M, N, K);
  }
}

// Round 3
// 184.269 us; speedup vs baseline: 1.6386x; 1.6386x over previous
//
#include <hip/hip_runtime.h>
#include <hip/hip_bf16.h>
#include <cstdint>

typedef __attribute__((ext_vector_type(8))) short short8;
typedef __attribute__((ext_vector_type(4))) float floatx4;

__device__ __forceinline__ unsigned short f2bf(float f) {
  union { float f; unsigned int i; } v; v.f = f;
  unsigned int r = v.i + 0x7FFFu + ((v.i >> 16) & 1u);
  return (unsigned short)(r >> 16);
}

__device__ __forceinline__ void async_copy16(const void* g, void* l) {
  __builtin_amdgcn_global_load_lds(
      (const __attribute__((address_space(1))) void*)g,
      (__attribute__((address_space(3))) void*)l, 16, 0, 0);
}

// ---------------------------------------------------------------------------
// fp32 -> bf16 bulk convert (8 floats / thread)
// ---------------------------------------------------------------------------
__global__ __launch_bounds__(256) void f32_to_bf16_kernel(
    const float* __restrict__ in, unsigned short* __restrict__ out, int n8) {
  int i = blockIdx.x * blockDim.x + threadIdx.x;
  if (i >= n8) return;
  const float4* p = (const float4*)in + (size_t)i * 2;
  float4 a = p[0], b = p[1];
  short8 r;
  r[0] = (short)f2bf(a.x); r[1] = (short)f2bf(a.y);
  r[2] = (short)f2bf(a.z); r[3] = (short)f2bf(a.w);
  r[4] = (short)f2bf(b.x); r[5] = (short)f2bf(b.y);
  r[6] = (short)f2bf(b.z); r[7] = (short)f2bf(b.w);
  *(short8*)(out + (size_t)i * 8) = r;
}

// ---------------------------------------------------------------------------
// Tiled GEMM: out[m][n] = sum_k A[m][k]*W[n][k] + bias[n].  bf16 in, fp32 acc.
// Block = 256 thr (4 waves), tile BM x BN, BK=64, global_load_lds staging.
// LDS layout: 16B chunk (row, col8) stored at slot row*8 + (col8 ^ (row&7))
// (XOR swizzle keeps the linear lane*16 order global_load_lds requires while
//  breaking the 128B-row-stride 16-way bank conflict -> ~2-way).
// Wave w covers (wm, wn) = ((w&1)*BM/2, (w>>1)*BN/2).
// ---------------------------------------------------------------------------
template <int BM, int BN, typename OutT>
__global__ __launch_bounds__(256) void gemm_tiled_kernel(
    const unsigned short* __restrict__ A, const unsigned short* __restrict__ W,
    const float* __restrict__ bias, OutT* __restrict__ out,
    int M, int N, int K) {
  constexpr int BK = 64;
  constexpr int MI = BM / 32;  // 16x16 m-tiles per wave
  constexpr int NI = BN / 32;  // 16x16 n-tiles per wave
  __shared__ __align__(16) unsigned short As[BM * BK];
  __shared__ __align__(16) unsigned short Ws[BN * BK];

  int tid = threadIdx.x, wave = tid >> 6, lane = tid & 63;
  int l16 = lane & 15, quad = lane >> 4;
  int bm = blockIdx.x, bn = blockIdx.y;
  int wm = (wave & 1) * (BM / 2), wn = (wave >> 1) * (BN / 2);

  floatx4 acc[MI][NI] = {};

  for (int kk = 0; kk < K; kk += BK) {
    __syncthreads();  // protect LDS from readers of previous tile
#pragma unroll
    for (int c = 0; c < MI; c++) {  // A: BM/32 chunks of 1KB per wave
      int ci = (wave * MI + c) * 64 + lane;
      int row = ci >> 3, col8 = (ci & 7) ^ (row & 7);
      async_copy16(A + (size_t)(bm * BM + row) * K + kk + col8 * 8,
                   As + (size_t)ci * 8);
    }
#pragma unroll
    for (int c = 0; c < NI; c++) {  // W: BN/32 chunks per wave
      int ci = (wave * NI + c) * 64 + lane;
      int row = ci >> 3, col8 = (ci & 7) ^ (row & 7);
      async_copy16(W + (size_t)(bn * BN + row) * K + kk + col8 * 8,
                   Ws + (size_t)ci * 8);
    }
    __syncthreads();  // implies vmcnt(0): staging complete

#pragma unroll
    for (int k2 = 0; k2 < 2; k2++) {  // two K=32 MFMA steps
      short8 a[MI], w8[NI];
#pragma unroll
      for (int mi = 0; mi < MI; mi++) {
        int row = wm + mi * 16 + l16;
        int slot = ((k2 * 4 + quad) ^ (row & 7));
        a[mi] = *(const short8*)(As + row * 64 + slot * 8);
      }
#pragma unroll
      for (int ni = 0; ni < NI; ni++) {
        int row = wn + ni * 16 + l16;
        int slot = ((k2 * 4 + quad) ^ (row & 7));
        w8[ni] = *(const short8*)(Ws + row * 64 + slot * 8);
      }
#pragma unroll
      for (int mi = 0; mi < MI; mi++)
#pragma unroll
        for (int ni = 0; ni < NI; ni++)
          acc[mi][ni] = __builtin_amdgcn_mfma_f32_16x16x32_bf16(
              a[mi], w8[ni], acc[mi][ni], 0, 0, 0);
    }
  }

#pragma unroll
  for (int ni = 0; ni < NI; ni++) {
    int col = bn * BN + wn + ni * 16 + l16;
    float bb = bias[col];
#pragma unroll
    for (int mi = 0; mi < MI; mi++) {
#pragma unroll
      for (int r = 0; r < 4; r++) {
        int row = bm * BM + wm + mi * 16 + quad * 4 + r;
        float v = acc[mi][ni][r] + bb;
        if constexpr (sizeof(OutT) == 2)
          out[(size_t)row * N + col] = (OutT)f2bf(v);
        else
          out[(size_t)row * N + col] = (OutT)v;
      }
    }
  }
}

// ---------------------------------------------------------------------------
// Fused attention. Block = (b, h, 64 q-rows), 4 waves x 16 q-rows.
// 64-row K/V chunks; K staged as Kb[m][d] (pad 70), V staged TRANSPOSED as
// Vt[d][m] (pad 70) so PV B-fragments are contiguous ds_read_b128.
// P round-trips through a PER-WAVE LDS buffer (no barrier needed: same-wave
// DS ordering). Pass A: streaming sumsq/max; pass B: softmax + PV.
// ---------------------------------------------------------------------------
__global__ __launch_bounds__(256) void attn_kernel(
    const unsigned short* __restrict__ qkv, unsigned short* __restrict__ attn_out) {
  constexpr int NSEQ = 2048, LD = 1536, DM = 512;
  constexpr int PK = 70;  // row pad (u16): word-stride 35 -> ~2-way banks
  const float scale = 0.125f;

  int qb = blockIdx.x, h = blockIdx.y, b = blockIdx.z;
  int tid = threadIdx.x, wave = tid >> 6, lane = tid & 63;
  int l16 = lane & 15, quad = lane >> 4;

  __shared__ __align__(16) unsigned short Kb[64 * PK];   // [m][d]
  __shared__ __align__(16) unsigned short Vt[64 * PK];   // [d][m]
  __shared__ __align__(16) unsigned short Pb[4][16 * PK];

  const unsigned short* base = qkv + (size_t)b * NSEQ * LD;

  int qrow = qb * 64 + wave * 16 + l16;
  const unsigned short* qptr = base + (size_t)qrow * LD + h * 64;
  short8 aq0 = *(const short8*)(qptr + quad * 8);
  short8 aq1 = *(const short8*)(qptr + 32 + quad * 8);

  // staging: thread t -> row sr = t>>2 (0..63), cols sc..sc+15
  int sr = tid >> 2, sc = (tid & 3) * 16;
  const unsigned short* ksrc = base + (size_t)sr * LD + 512 + h * 64 + sc;
  const unsigned short* vsrc = base + (size_t)sr * LD + 1024 + h * 64 + sc;

  // ---------------- pass A: row sumsq + max ----------------
  float sumsq[4] = {0.f, 0.f, 0.f, 0.f};
  float mx[4] = {-1e30f, -1e30f, -1e30f, -1e30f};

  for (int mc = 0; mc < NSEQ; mc += 64) {
    *(short8*)(&Kb[sr * PK + sc]) = *(const short8*)(ksrc + (size_t)mc * LD);
    *(short8*)(&Kb[sr * PK + sc + 8]) = *(const short8*)(ksrc + (size_t)mc * LD + 8);
    __syncthreads();
#pragma unroll
    for (int st = 0; st < 4; st++) {
      floatx4 acc = {0.f, 0.f, 0.f, 0.f};
      short8 b0 = *(const short8*)(&Kb[(st * 16 + l16) * PK + quad * 8]);
      short8 b1 = *(const short8*)(&Kb[(st * 16 + l16) * PK + 32 + quad * 8]);
      acc = __builtin_amdgcn_mfma_f32_16x16x32_bf16(aq0, b0, acc, 0, 0, 0);
      acc = __builtin_amdgcn_mfma_f32_16x16x32_bf16(aq1, b1, acc, 0, 0, 0);
#pragma unroll
      for (int r = 0; r < 4; r++) {
        float s = acc[r] * scale;
        sumsq[r] += s * s;
        mx[r] = fmaxf(mx[r], s);
      }
    }
    __syncthreads();
  }

#pragma unroll
  for (int r = 0; r < 4; r++) {
#pragma unroll
    for (int m = 1; m <= 8; m <<= 1) {
      sumsq[r] += __shfl_xor(sumsq[r], m, 64);
      mx[r] = fmaxf(mx[r], __shfl_xor(mx[r], m, 64));
    }
  }
  float invden[4];
#pragma unroll
  for (int r = 0; r < 4; r++) invden[r] = 1.f / (sqrtf(sumsq[r]) + 1e-6f);

  // ---------------- pass B: softmax + P*V ----------------
  floatx4 o[4] = {};
  float lsum[4] = {0.f, 0.f, 0.f, 0.f};

  for (int mc = 0; mc < NSEQ; mc += 64) {
    short8 k0 = *(const short8*)(ksrc + (size_t)mc * LD);
    short8 k1 = *(const short8*)(ksrc + (size_t)mc * LD + 8);
    short8 v0 = *(const short8*)(vsrc + (size_t)mc * LD);
    short8 v1 = *(const short8*)(vsrc + (size_t)mc * LD + 8);
    *(short8*)(&Kb[sr * PK + sc]) = k0;
    *(short8*)(&Kb[sr * PK + sc + 8]) = k1;
#pragma unroll
    for (int j = 0; j < 8; j++) {
      Vt[(sc + j) * PK + sr] = (unsigned short)v0[j];
      Vt[(sc + 8 + j) * PK + sr] = (unsigned short)v1[j];
    }
    __syncthreads();

#pragma unroll
    for (int st = 0; st < 4; st++) {
      floatx4 acc = {0.f, 0.f, 0.f, 0.f};
      short8 b0 = *(const short8*)(&Kb[(st * 16 + l16) * PK + quad * 8]);
      short8 b1 = *(const short8*)(&Kb[(st * 16 + l16) * PK + 32 + quad * 8]);
      acc = __builtin_amdgcn_mfma_f32_16x16x32_bf16(aq0, b0, acc, 0, 0, 0);
      acc = __builtin_amdgcn_mfma_f32_16x16x32_bf16(aq1, b1, acc, 0, 0, 0);
#pragma unroll
      for (int r = 0; r < 4; r++) {
        float s = acc[r] * scale;
        float p = __expf((s - mx[r]) * invden[r]);
        lsum[r] += p;
        Pb[wave][(quad * 4 + r) * PK + st * 16 + l16] = f2bf(p);
      }
    }
    // same-wave DS ordering: no barrier needed before reading Pb[wave]
    short8 ap0 = *(const short8*)(&Pb[wave][l16 * PK + quad * 8]);
    short8 ap1 = *(const short8*)(&Pb[wave][l16 * PK + 32 + quad * 8]);
#pragma unroll
    for (int dt = 0; dt < 4; dt++) {
      short8 bv0 = *(const short8*)(&Vt[(dt * 16 + l16) * PK + quad * 8]);
      short8 bv1 = *(const short8*)(&Vt[(dt * 16 + l16) * PK + 32 + quad * 8]);
      o[dt] = __builtin_amdgcn_mfma_f32_16x16x32_bf16(ap0, bv0, o[dt], 0, 0, 0);
      o[dt] = __builtin_amdgcn_mfma_f32_16x16x32_bf16(ap1, bv1, o[dt], 0, 0, 0);
    }
    __syncthreads();
  }

#pragma unroll
  for (int r = 0; r < 4; r++)
#pragma unroll
    for (int m = 1; m <= 8; m <<= 1) lsum[r] += __shfl_xor(lsum[r], m, 64);

  int nrow_base = qb * 64 + wave * 16 + quad * 4;
  size_t ob = (size_t)b * NSEQ * DM;
#pragma unroll
  for (int r = 0; r < 4; r++) {
    float inv = 1.f / lsum[r];
    size_t rowoff = ob + (size_t)(nrow_base + r) * DM + h * 64 + l16;
    attn_out[rowoff + 0] = f2bf(o[0][r] * inv);
    attn_out[rowoff + 16] = f2bf(o[1][r] * inv);
    attn_out[rowoff + 32] = f2bf(o[2][r] * inv);
    attn_out[rowoff + 48] = f2bf(o[3][r] * inv);
  }
}

// ---------------------------------------------------------------------------
extern "C" void kernel_launch(void* const* d_in, const int* in_sizes, int n_in,
                              void* d_out, int out_size, void* d_ws, size_t ws_size,
                              hipStream_t stream) {
  const float* x = (const float*)d_in[0];       // (2,2048,512) fp32
  const float* qkv_w = (const float*)d_in[1];   // (1536,512)
  const float* qkv_b = (const float*)d_in[2];   // (1536,)
  const float* proj_w = (const float*)d_in[3];  // (512,512)
  const float* proj_b = (const float*)d_in[4];  // (512,)
  float* out = (float*)d_out;                   // (2,2048,512) fp32

  unsigned short* xb = (unsigned short*)d_ws;             // 4096*512
  unsigned short* qkvw_b = xb + (size_t)4096 * 512;       // 1536*512
  unsigned short* projw_b = qkvw_b + (size_t)1536 * 512;  // 512*512
  unsigned short* qkv = projw_b + (size_t)512 * 512;      // 4096*1536
  unsigned short* attn_out = qkv + (size_t)4096 * 1536;   // 4096*512

  {
    int n8 = (4096 * 512) / 8;
    f32_to_bf16_kernel<<<(n8 + 255) / 256, 256, 0, stream>>>(x, xb, n8);
    n8 = (1536 * 512) / 8;
    f32_to_bf16_kernel<<<(n8 + 255) / 256, 256, 0, stream>>>(qkv_w, qkvw_b, n8);
    n8 = (512 * 512) / 8;
    f32_to_bf16_kernel<<<(n8 + 255) / 256, 256, 0, stream>>>(proj_w, projw_b, n8);
  }
  // 1) qkv = x @ qkv_w^T + qkv_b : M=4096 N=1536 K=512, tile 128x64 -> 768 blocks
  gemm_tiled_kernel<128, 64, unsigned short>
      <<<dim3(4096 / 128, 1536 / 64), 256, 0, stream>>>(
          xb, qkvw_b, qkv_b, qkv, 4096, 1536, 512);
  // 2) fused attention
  attn_kernel<<<dim3(32, 8, 2), 256, 0, stream>>>(qkv, attn_out);
  // 3) out = attn_out @ proj_w^T + proj_b : M=4096 N=512 K=512, tile 64x64 -> 512 blocks
  gemm_tiled_kernel<64, 64, float>
      <<<dim3(4096 / 64, 512 / 64), 256, 0, stream>>>(
          attn_out, projw_b, proj_b, out, 4096, 512, 512);
}

// Round 4
// 156.047 us; speedup vs baseline: 1.9350x; 1.1809x over previous
//
#include <hip/hip_runtime.h>
#include <hip/hip_bf16.h>
#include <cstdint>

typedef __attribute__((ext_vector_type(8))) short short8;
typedef __attribute__((ext_vector_type(4))) float floatx4;

__device__ __forceinline__ unsigned short f2bf(float f) {
  union { float f; unsigned int i; } v; v.f = f;
  unsigned int r = v.i + 0x7FFFu + ((v.i >> 16) & 1u);
  return (unsigned short)(r >> 16);
}

__device__ __forceinline__ void async_copy16(const void* g, void* l) {
  __builtin_amdgcn_global_load_lds(
      (const __attribute__((address_space(1))) void*)g,
      (__attribute__((address_space(3))) void*)l, 16, 0, 0);
}

// ---------------------------------------------------------------------------
// fp32 -> bf16 bulk convert (8 floats / thread)
// ---------------------------------------------------------------------------
__global__ __launch_bounds__(256) void f32_to_bf16_kernel(
    const float* __restrict__ in, unsigned short* __restrict__ out, int n8) {
  int i = blockIdx.x * blockDim.x + threadIdx.x;
  if (i >= n8) return;
  const float4* p = (const float4*)in + (size_t)i * 2;
  float4 a = p[0], b = p[1];
  short8 r;
  r[0] = (short)f2bf(a.x); r[1] = (short)f2bf(a.y);
  r[2] = (short)f2bf(a.z); r[3] = (short)f2bf(a.w);
  r[4] = (short)f2bf(b.x); r[5] = (short)f2bf(b.y);
  r[6] = (short)f2bf(b.z); r[7] = (short)f2bf(b.w);
  *(short8*)(out + (size_t)i * 8) = r;
}

// ---------------------------------------------------------------------------
// Tiled GEMM (unchanged from R3): out = A @ W^T + bias, bf16 in, fp32 acc.
// ---------------------------------------------------------------------------
template <int BM, int BN, typename OutT>
__global__ __launch_bounds__(256) void gemm_tiled_kernel(
    const unsigned short* __restrict__ A, const unsigned short* __restrict__ W,
    const float* __restrict__ bias, OutT* __restrict__ out,
    int M, int N, int K) {
  constexpr int BK = 64;
  constexpr int MI = BM / 32;
  constexpr int NI = BN / 32;
  __shared__ __align__(16) unsigned short As[BM * BK];
  __shared__ __align__(16) unsigned short Ws[BN * BK];

  int tid = threadIdx.x, wave = tid >> 6, lane = tid & 63;
  int l16 = lane & 15, quad = lane >> 4;
  int bm = blockIdx.x, bn = blockIdx.y;
  int wm = (wave & 1) * (BM / 2), wn = (wave >> 1) * (BN / 2);

  floatx4 acc[MI][NI] = {};

  for (int kk = 0; kk < K; kk += BK) {
    __syncthreads();
#pragma unroll
    for (int c = 0; c < MI; c++) {
      int ci = (wave * MI + c) * 64 + lane;
      int row = ci >> 3, col8 = (ci & 7) ^ (row & 7);
      async_copy16(A + (size_t)(bm * BM + row) * K + kk + col8 * 8,
                   As + (size_t)ci * 8);
    }
#pragma unroll
    for (int c = 0; c < NI; c++) {
      int ci = (wave * NI + c) * 64 + lane;
      int row = ci >> 3, col8 = (ci & 7) ^ (row & 7);
      async_copy16(W + (size_t)(bn * BN + row) * K + kk + col8 * 8,
                   Ws + (size_t)ci * 8);
    }
    __syncthreads();

#pragma unroll
    for (int k2 = 0; k2 < 2; k2++) {
      short8 a[MI], w8[NI];
#pragma unroll
      for (int mi = 0; mi < MI; mi++) {
        int row = wm + mi * 16 + l16;
        int slot = ((k2 * 4 + quad) ^ (row & 7));
        a[mi] = *(const short8*)(As + row * 64 + slot * 8);
      }
#pragma unroll
      for (int ni = 0; ni < NI; ni++) {
        int row = wn + ni * 16 + l16;
        int slot = ((k2 * 4 + quad) ^ (row & 7));
        w8[ni] = *(const short8*)(Ws + row * 64 + slot * 8);
      }
#pragma unroll
      for (int mi = 0; mi < MI; mi++)
#pragma unroll
        for (int ni = 0; ni < NI; ni++)
          acc[mi][ni] = __builtin_amdgcn_mfma_f32_16x16x32_bf16(
              a[mi], w8[ni], acc[mi][ni], 0, 0, 0);
    }
  }

#pragma unroll
  for (int ni = 0; ni < NI; ni++) {
    int col = bn * BN + wn + ni * 16 + l16;
    float bb = bias[col];
#pragma unroll
    for (int mi = 0; mi < MI; mi++) {
#pragma unroll
      for (int r = 0; r < 4; r++) {
        int row = bm * BM + wm + mi * 16 + quad * 4 + r;
        float v = acc[mi][ni][r] + bb;
        if constexpr (sizeof(OutT) == 2)
          out[(size_t)row * N + col] = (OutT)f2bf(v);
        else
          out[(size_t)row * N + col] = (OutT)v;
      }
    }
  }
}

// ---------------------------------------------------------------------------
// V transpose: qkv[b][n][1024 + h*64 + d] -> vt[(b*8+h)*64 + d][n]
// Grid (32 n-blocks, 16 bh). 64x64 tile via LDS (stride 72 breaks banks).
// ---------------------------------------------------------------------------
__global__ __launch_bounds__(256) void v_transpose_kernel(
    const unsigned short* __restrict__ qkv, unsigned short* __restrict__ vt) {
  __shared__ __align__(16) unsigned short T[64 * 72];
  int nb = blockIdx.x, bh = blockIdx.y;
  int b = bh >> 3, h = bh & 7;
  int t = threadIdx.x;
#pragma unroll
  for (int c = 0; c < 2; c++) {
    int ci = c * 256 + t;
    int row = ci >> 3, ch = ci & 7;
    *(short8*)(T + row * 72 + ch * 8) = *(const short8*)(
        qkv + (size_t)(b * 2048 + nb * 64 + row) * 1536 + 1024 + h * 64 + ch * 8);
  }
  __syncthreads();
  int d = t & 63, nblk = t >> 6;  // nblk is wave-uniform: lane-banks = d/2 (2-way)
  short8 v0, v1;
#pragma unroll
  for (int i = 0; i < 8; i++) v0[i] = (short)T[(nblk * 16 + i) * 72 + d];
#pragma unroll
  for (int i = 0; i < 8; i++) v1[i] = (short)T[(nblk * 16 + 8 + i) * 72 + d];
  size_t orow = ((size_t)bh * 64 + d) * 2048 + nb * 64 + nblk * 16;
  *(short8*)(vt + orow) = v0;
  *(short8*)(vt + orow + 8) = v1;
}

// ---------------------------------------------------------------------------
// Fused attention, shared-Q design. Block = (qb 64 q-rows, h, b), 4 waves.
// All waves hold A-frags for the full 64 q-rows. 128-kv chunks:
//   pass A: QK^T kv-sliced across waves -> raw sumsq (no max needed: |s|<=|s|_2
//           bounds the exp argument to [-1,1]).
//   pass B: QK^T again, p = exp(acc*invk), P -> swizzled LDS; PV with d-tile
//           = wave over all 128 kv (full-k accumulate, no cross-wave O).
// K staged [kv][d] swizzled; V staged from pre-transposed vt as [d][kv].
// ---------------------------------------------------------------------------
__global__ __launch_bounds__(256) void attn_kernel(
    const unsigned short* __restrict__ qkv,
    const unsigned short* __restrict__ vt,
    unsigned short* __restrict__ attn_out) {
  constexpr int NSEQ = 2048, LD = 1536, DM = 512;
  const float scale = 0.125f;

  __shared__ __align__(16) unsigned short Kb[128 * 64];   // [kv][d-slot^]
  __shared__ __align__(16) unsigned short Vtb[64 * 128];  // [d][kv-slot^]
  __shared__ __align__(16) unsigned short Pb[64 * 128];   // [q][kv-slot^]
  __shared__ float Red[4][64];

  int qb = blockIdx.x, h = blockIdx.y, b = blockIdx.z;
  int tid = threadIdx.x, wave = tid >> 6, lane = tid & 63;
  int l16 = lane & 15, quad = lane >> 4;

  const unsigned short* base = qkv + (size_t)b * NSEQ * LD;
  const unsigned short* vbase = vt + (size_t)(b * 8 + h) * 64 * NSEQ;

  // Q A-frags for all 4 m-tiles (replicated per wave; L2 broadcast)
  short8 aq[4][2];
#pragma unroll
  for (int mi = 0; mi < 4; mi++) {
    const unsigned short* qp =
        base + (size_t)(qb * 64 + mi * 16 + l16) * LD + h * 64;
    aq[mi][0] = *(const short8*)(qp + quad * 8);
    aq[mi][1] = *(const short8*)(qp + 32 + quad * 8);
  }

  // ---------------- pass A: raw sumsq ----------------
  float sumsq[4][4] = {};
  for (int mc = 0; mc < NSEQ; mc += 128) {
    __syncthreads();
#pragma unroll
    for (int c = 0; c < 4; c++) {
      int ci = (wave * 4 + c) * 64 + lane;
      int row = ci >> 3, sc = (ci & 7) ^ (row & 7);
      async_copy16(base + (size_t)(mc + row) * LD + 512 + h * 64 + sc * 8,
                   Kb + (size_t)ci * 8);
    }
    __syncthreads();
#pragma unroll
    for (int st = 0; st < 2; st++) {
      floatx4 acc[4] = {};
      int row = wave * 32 + st * 16 + l16;
#pragma unroll
      for (int k2 = 0; k2 < 2; k2++) {
        short8 bk = *(const short8*)(Kb + row * 64 +
                                     (((k2 * 4 + quad) ^ (row & 7)) * 8));
#pragma unroll
        for (int mi = 0; mi < 4; mi++)
          acc[mi] = __builtin_amdgcn_mfma_f32_16x16x32_bf16(aq[mi][k2], bk,
                                                            acc[mi], 0, 0, 0);
      }
#pragma unroll
      for (int mi = 0; mi < 4; mi++)
#pragma unroll
        for (int r = 0; r < 4; r++) sumsq[mi][r] += acc[mi][r] * acc[mi][r];
    }
  }

#pragma unroll
  for (int mi = 0; mi < 4; mi++)
#pragma unroll
    for (int r = 0; r < 4; r++)
#pragma unroll
      for (int m = 1; m <= 8; m <<= 1)
        sumsq[mi][r] += __shfl_xor(sumsq[mi][r], m, 64);
  if (l16 == 0) {
#pragma unroll
    for (int mi = 0; mi < 4; mi++)
#pragma unroll
      for (int r = 0; r < 4; r++)
        Red[wave][mi * 16 + quad * 4 + r] = sumsq[mi][r];
  }
  __syncthreads();
  float invk[4][4];
#pragma unroll
  for (int mi = 0; mi < 4; mi++)
#pragma unroll
    for (int r = 0; r < 4; r++) {
      int q = mi * 16 + quad * 4 + r;
      float tot = Red[0][q] + Red[1][q] + Red[2][q] + Red[3][q];
      invk[mi][r] = scale / (scale * sqrtf(tot) + 1e-6f);
    }

  // ---------------- pass B: softmax + PV ----------------
  floatx4 o[4] = {};  // o[mi] for d-tile = wave
  float lsum[4][4] = {};

  for (int mc = 0; mc < NSEQ; mc += 128) {
    __syncthreads();  // prev chunk's PV reads done
#pragma unroll
    for (int c = 0; c < 4; c++) {
      int ci = (wave * 4 + c) * 64 + lane;
      int row = ci >> 3, sc = (ci & 7) ^ (row & 7);
      async_copy16(base + (size_t)(mc + row) * LD + 512 + h * 64 + sc * 8,
                   Kb + (size_t)ci * 8);
    }
#pragma unroll
    for (int c = 0; c < 4; c++) {
      int ci = (wave * 4 + c) * 64 + lane;
      int d = ci >> 4, sc = (ci & 15) ^ (d & 15);
      async_copy16(vbase + (size_t)d * NSEQ + mc + sc * 8,
                   Vtb + (size_t)ci * 8);
    }
    __syncthreads();  // staging complete

#pragma unroll
    for (int st = 0; st < 2; st++) {
      floatx4 acc[4] = {};
      int row = wave * 32 + st * 16 + l16;
#pragma unroll
      for (int k2 = 0; k2 < 2; k2++) {
        short8 bk = *(const short8*)(Kb + row * 64 +
                                     (((k2 * 4 + quad) ^ (row & 7)) * 8));
#pragma unroll
        for (int mi = 0; mi < 4; mi++)
          acc[mi] = __builtin_amdgcn_mfma_f32_16x16x32_bf16(aq[mi][k2], bk,
                                                            acc[mi], 0, 0, 0);
      }
      int kvc = wave * 4 + st * 2 + (l16 >> 3);
#pragma unroll
      for (int mi = 0; mi < 4; mi++)
#pragma unroll
        for (int r = 0; r < 4; r++) {
          float p = __expf(acc[mi][r] * invk[mi][r]);
          lsum[mi][r] += p;
          int q = mi * 16 + quad * 4 + r;
          Pb[q * 128 + ((kvc ^ (q & 15)) * 8) + (l16 & 7)] = f2bf(p);
        }
    }
    __syncthreads();  // P visible to all waves

    short8 bv[4];
    int d = wave * 16 + l16;
#pragma unroll
    for (int ks = 0; ks < 4; ks++)
      bv[ks] = *(const short8*)(Vtb + d * 128 + (((ks * 4 + quad) ^ l16) * 8));
#pragma unroll
    for (int mi = 0; mi < 4; mi++) {
#pragma unroll
      for (int ks = 0; ks < 4; ks++) {
        short8 ap = *(const short8*)(Pb + (mi * 16 + l16) * 128 +
                                     (((ks * 4 + quad) ^ l16) * 8));
        o[mi] = __builtin_amdgcn_mfma_f32_16x16x32_bf16(ap, bv[ks], o[mi],
                                                        0, 0, 0);
      }
    }
  }

  // lsum: reduce over l16 lanes, then across waves (kv slices) via LDS
#pragma unroll
  for (int mi = 0; mi < 4; mi++)
#pragma unroll
    for (int r = 0; r < 4; r++)
#pragma unroll
      for (int m = 1; m <= 8; m <<= 1)
        lsum[mi][r] += __shfl_xor(lsum[mi][r], m, 64);
  __syncthreads();  // all waves done reading Pb/Red before Red overwrite
  if (l16 == 0) {
#pragma unroll
    for (int mi = 0; mi < 4; mi++)
#pragma unroll
      for (int r = 0; r < 4; r++)
        Red[wave][mi * 16 + quad * 4 + r] = lsum[mi][r];
  }
  __syncthreads();

  size_t ob = ((size_t)b * NSEQ + qb * 64) * DM + h * 64 + wave * 16 + l16;
#pragma unroll
  for (int mi = 0; mi < 4; mi++)
#pragma unroll
    for (int r = 0; r < 4; r++) {
      int q = mi * 16 + quad * 4 + r;
      float tot = Red[0][q] + Red[1][q] + Red[2][q] + Red[3][q];
      attn_out[ob + (size_t)q * DM] = f2bf(o[mi][r] / tot);
    }
}

// ---------------------------------------------------------------------------
extern "C" void kernel_launch(void* const* d_in, const int* in_sizes, int n_in,
                              void* d_out, int out_size, void* d_ws, size_t ws_size,
                              hipStream_t stream) {
  const float* x = (const float*)d_in[0];
  const float* qkv_w = (const float*)d_in[1];
  const float* qkv_b = (const float*)d_in[2];
  const float* proj_w = (const float*)d_in[3];
  const float* proj_b = (const float*)d_in[4];
  float* out = (float*)d_out;

  unsigned short* xb = (unsigned short*)d_ws;             // 4096*512
  unsigned short* qkvw_b = xb + (size_t)4096 * 512;       // 1536*512
  unsigned short* projw_b = qkvw_b + (size_t)1536 * 512;  // 512*512
  unsigned short* qkv = projw_b + (size_t)512 * 512;      // 4096*1536
  unsigned short* attn_out = qkv + (size_t)4096 * 1536;   // 4096*512
  unsigned short* vt = attn_out + (size_t)4096 * 512;     // 16*64*2048

  {
    int n8 = (4096 * 512) / 8;
    f32_to_bf16_kernel<<<(n8 + 255) / 256, 256, 0, stream>>>(x, xb, n8);
    n8 = (1536 * 512) / 8;
    f32_to_bf16_kernel<<<(n8 + 255) / 256, 256, 0, stream>>>(qkv_w, qkvw_b, n8);
    n8 = (512 * 512) / 8;
    f32_to_bf16_kernel<<<(n8 + 255) / 256, 256, 0, stream>>>(proj_w, projw_b, n8);
  }
  // 1) qkv = x @ qkv_w^T + qkv_b
  gemm_tiled_kernel<128, 64, unsigned short>
      <<<dim3(4096 / 128, 1536 / 64), 256, 0, stream>>>(
          xb, qkvw_b, qkv_b, qkv, 4096, 1536, 512);
  // 1b) V transpose into vt[(b*8+h)*64 + d][n]
  v_transpose_kernel<<<dim3(32, 16), 256, 0, stream>>>(qkv, vt);
  // 2) fused attention
  attn_kernel<<<dim3(32, 8, 2), 256, 0, stream>>>(qkv, vt, attn_out);
  // 3) out = attn_out @ proj_w^T + proj_b
  gemm_tiled_kernel<64, 64, float>
      <<<dim3(4096 / 64, 512 / 64), 256, 0, stream>>>(
          attn_out, projw_b, proj_b, out, 4096, 512, 512);
}